// Round 1
// baseline (1215.554 us; speedup 1.0000x reference)
//
#include <hip/hip_runtime.h>
#include <hip/hip_bf16.h>

typedef __attribute__((ext_vector_type(8))) short short8;
typedef __attribute__((ext_vector_type(4))) float f32x4;

__device__ inline unsigned short f2bfu(float x) {
  __hip_bfloat16 h = __float2bfloat16(x);
  return __builtin_bit_cast(unsigned short, h);
}

// ---------------- cast fp32 -> bf16, 4 elems/thread ----------------
__global__ __launch_bounds__(256) void cast_f32_bf16(const float4* __restrict__ src,
                                                     unsigned long long* __restrict__ dst,
                                                     int n4) {
  int i = blockIdx.x * 256 + threadIdx.x;
  if (i >= n4) return;
  float4 v = src[i];
  unsigned long long r = (unsigned long long)f2bfu(v.x)
                       | ((unsigned long long)f2bfu(v.y) << 16)
                       | ((unsigned long long)f2bfu(v.z) << 32)
                       | ((unsigned long long)f2bfu(v.w) << 48);
  dst[i] = r;
}

// ---------------- GEMM: C[M,N] = A[M,K] * B[N,K]^T (bf16 in, OutT out) ----------------
__device__ inline void store_cvt(float* p, float v) { *p = v; }
__device__ inline void store_cvt(__hip_bfloat16* p, float v) { *p = __float2bfloat16(v); }

template <typename OutT>
__global__ __launch_bounds__(256) void gemm_bt(const __hip_bfloat16* __restrict__ A,
                                               const __hip_bfloat16* __restrict__ B,
                                               OutT* __restrict__ C,
                                               int M, int N, int K) {
  __shared__ __align__(16) __hip_bfloat16 As[128][40];  // +8 pad: 2-way banks, 16B aligned rows
  __shared__ __align__(16) __hip_bfloat16 Bs[128][40];
  const int tid = threadIdx.x;
  const int wave = tid >> 6, lane = tid & 63;
  const int wm = wave >> 1, wn = wave & 1;          // 2x2 waves -> 64x64 each
  const int quad = lane >> 4, l16 = lane & 15;
  const int m0 = blockIdx.y * 128, n0 = blockIdx.x * 128;
  const int r0 = tid >> 2;                          // staging: 4 threads per row
  const int c0 = (tid & 3) * 8;
  f32x4 acc[4][4] = {};
  for (int kt = 0; kt < K; kt += 32) {
#pragma unroll
    for (int i = 0; i < 2; i++) {
      int row = i * 64 + r0;
      *(uint4*)&As[row][c0] = *(const uint4*)&A[(size_t)(m0 + row) * K + kt + c0];
      *(uint4*)&Bs[row][c0] = *(const uint4*)&B[(size_t)(n0 + row) * K + kt + c0];
    }
    __syncthreads();
    short8 af[4], bfr[4];
#pragma unroll
    for (int t = 0; t < 4; t++) {
      af[t]  = *(const short8*)&As[wm * 64 + t * 16 + l16][quad * 8];
      bfr[t] = *(const short8*)&Bs[wn * 64 + t * 16 + l16][quad * 8];
    }
#pragma unroll
    for (int im = 0; im < 4; im++)
#pragma unroll
      for (int in = 0; in < 4; in++)
        acc[im][in] = __builtin_amdgcn_mfma_f32_16x16x32_bf16(af[im], bfr[in], acc[im][in], 0, 0, 0);
    __syncthreads();
  }
#pragma unroll
  for (int im = 0; im < 4; im++)
#pragma unroll
    for (int in = 0; in < 4; in++) {
      int col = n0 + wn * 64 + in * 16 + l16;
#pragma unroll
      for (int r = 0; r < 4; r++) {
        int row = m0 + wm * 64 + im * 16 + quad * 4 + r;
        store_cvt(&C[(size_t)row * N + col], acc[im][in][r]);
      }
    }
}

// ---------------- RMSNorm + RoPE, scatter to attention layouts ----------------
// qkv: [8192][3072] bf16. slots 0..15 = q heads, 16..19 = k heads, 20..23 = v heads.
// qb: (b,h,t,d)  kb/vb: (b,hkv,t,d)
__global__ __launch_bounds__(128) void norm_rope(const __hip_bfloat16* __restrict__ qkv,
                                                 __hip_bfloat16* __restrict__ qb,
                                                 __hip_bfloat16* __restrict__ kb,
                                                 __hip_bfloat16* __restrict__ vb) {
  const int token = blockIdx.y;   // 0..8191
  const int slot = blockIdx.x;    // 0..23
  const int d = threadIdx.x;      // 0..127
  const int b = token >> 11, t = token & 2047;
  float val = __bfloat162float(qkv[(size_t)token * 3072 + slot * 128 + d]);
  if (slot >= 20) {  // v: plain cast, no norm/rope
    vb[(((size_t)(b * 4 + (slot - 20))) * 2048 + t) * 128 + d] = __float2bfloat16(val);
    return;
  }
  // RMS norm over D=128
  float ss = val * val;
#pragma unroll
  for (int m = 1; m < 64; m <<= 1) ss += __shfl_xor(ss, m, 64);
  __shared__ float red[2];
  __shared__ float rowv[128];
  if ((threadIdx.x & 63) == 0) red[threadIdx.x >> 6] = ss;
  __syncthreads();
  float rinv = rsqrtf((red[0] + red[1]) * (1.0f / 128.0f) + 1.1920929e-7f);
  rowv[d] = val * rinv;
  __syncthreads();
  int i = d & 63;
  float x1 = rowv[i], x2 = rowv[i + 64];
  float inv_freq = expf(-(float)i * (9.210340371976184f / 64.0f));  // 10000^(-i/64)
  float ph = (float)t * inv_freq;
  float c = cosf(ph), s = sinf(ph);
  float outv = (d < 64) ? (x1 * c + x2 * s) : (x2 * c - x1 * s);
  if (slot < 16)
    qb[(((size_t)(b * 16 + slot)) * 2048 + t) * 128 + d] = __float2bfloat16(outv);
  else
    kb[(((size_t)(b * 4 + (slot - 16))) * 2048 + t) * 128 + d] = __float2bfloat16(outv);
}

// ---------------- causal GQA flash attention ----------------
// grid (T/64, B*H), 256 threads. qb (b,h,t,d); kb,vb (b,hkv,t,d); attnb (b,t,h*128+d)
__global__ __launch_bounds__(256) void flash_attn(const __hip_bfloat16* __restrict__ qb,
                                                  const __hip_bfloat16* __restrict__ kb,
                                                  const __hip_bfloat16* __restrict__ vb,
                                                  __hip_bfloat16* __restrict__ attnb) {
  const int qt = blockIdx.x, bh = blockIdx.y;
  const int b = bh >> 4, h = bh & 15, hkv = h >> 2;
  const int q0 = qt * 64;
  const __hip_bfloat16* Q  = qb + ((size_t)(b * 16 + h) * 2048 + q0) * 128;
  const __hip_bfloat16* Kp = kb + ((size_t)(b * 4 + hkv) * 2048) * 128;
  const __hip_bfloat16* Vp = vb + ((size_t)(b * 4 + hkv) * 2048) * 128;

  __shared__ __align__(16) __hip_bfloat16 Qs[64][136];
  __shared__ __align__(16) __hip_bfloat16 Ks[64][136];
  __shared__ __align__(16) __hip_bfloat16 Vt[128][72];    // transposed: [d][t]
  __shared__ __align__(16) __hip_bfloat16 Ps[4][16][72];  // per-wave P tile

  const int tid = threadIdx.x;
  const int wave = tid >> 6, lane = tid & 63;
  const int quad = lane >> 4, l16 = lane & 15;
  const int srow = tid >> 4;          // staging row (16 chunks of 8 per 128-col row)
  const int sc8 = (tid & 15) * 8;
  const float scale = 0.08838834764831845f;  // 1/sqrt(128)

  // stage Q once (64x128)
#pragma unroll
  for (int i = 0; i < 4; i++) {
    int row = i * 16 + srow;
    *(uint4*)&Qs[row][sc8] = *(const uint4*)&Q[(size_t)row * 128 + sc8];
  }

  f32x4 o[8] = {};
  float m_i[4], l_i[4];
#pragma unroll
  for (int r = 0; r < 4; r++) { m_i[r] = -1e30f; l_i[r] = 0.f; }

  const int ktmax = qt;
  for (int kt = 0; kt <= ktmax; kt++) {
    // stage K (row-major) and V (transposed)
#pragma unroll
    for (int i = 0; i < 4; i++) {
      int row = i * 16 + srow;
      *(uint4*)&Ks[row][sc8] = *(const uint4*)&Kp[((size_t)(kt * 64 + row)) * 128 + sc8];
      uint4 vv = *(const uint4*)&Vp[((size_t)(kt * 64 + row)) * 128 + sc8];
      const __hip_bfloat16* pv = (const __hip_bfloat16*)&vv;
#pragma unroll
      for (int j = 0; j < 8; j++) Vt[sc8 + j][row] = pv[j];
    }
    __syncthreads();

    // S = Q K^T  (16 rows per wave x 64 cols)
    short8 aq[4];
#pragma unroll
    for (int dk = 0; dk < 4; dk++)
      aq[dk] = *(const short8*)&Qs[wave * 16 + l16][dk * 32 + quad * 8];
    f32x4 s[4];
#pragma unroll
    for (int nt = 0; nt < 4; nt++) {
      f32x4 a = {0.f, 0.f, 0.f, 0.f};
#pragma unroll
      for (int dk = 0; dk < 4; dk++) {
        short8 bk = *(const short8*)&Ks[nt * 16 + l16][dk * 32 + quad * 8];
        a = __builtin_amdgcn_mfma_f32_16x16x32_bf16(aq[dk], bk, a, 0, 0, 0);
      }
      s[nt] = a;
    }

    // scale + causal mask + online softmax
    const bool diag = (kt == ktmax);
    float mt[4] = {-1e30f, -1e30f, -1e30f, -1e30f};
#pragma unroll
    for (int nt = 0; nt < 4; nt++)
#pragma unroll
      for (int r = 0; r < 4; r++) {
        float x = s[nt][r] * scale;
        if (diag) {
          int qrow = q0 + wave * 16 + quad * 4 + r;
          int kcol = kt * 64 + nt * 16 + l16;
          if (kcol > qrow) x = -1e30f;
        }
        s[nt][r] = x;
        mt[r] = fmaxf(mt[r], x);
      }
#pragma unroll
    for (int r = 0; r < 4; r++)
#pragma unroll
      for (int mm = 1; mm < 16; mm <<= 1)
        mt[r] = fmaxf(mt[r], __shfl_xor(mt[r], mm, 64));
    float alpha[4];
#pragma unroll
    for (int r = 0; r < 4; r++) {
      float mn = fmaxf(m_i[r], mt[r]);
      alpha[r] = __expf(m_i[r] - mn);
      m_i[r] = mn;
    }
    float rowsum[4] = {0.f, 0.f, 0.f, 0.f};
#pragma unroll
    for (int nt = 0; nt < 4; nt++)
#pragma unroll
      for (int r = 0; r < 4; r++) {
        float p = __expf(s[nt][r] - m_i[r]);
        s[nt][r] = p;
        rowsum[r] += p;
      }
#pragma unroll
    for (int r = 0; r < 4; r++) {
#pragma unroll
      for (int mm = 1; mm < 16; mm <<= 1) rowsum[r] += __shfl_xor(rowsum[r], mm, 64);
      l_i[r] = l_i[r] * alpha[r] + rowsum[r];
    }
#pragma unroll
    for (int vt = 0; vt < 8; vt++)
#pragma unroll
      for (int r = 0; r < 4; r++) o[vt][r] *= alpha[r];

    // P (C-layout) -> LDS -> A-layout
#pragma unroll
    for (int nt = 0; nt < 4; nt++)
#pragma unroll
      for (int r = 0; r < 4; r++)
        Ps[wave][quad * 4 + r][nt * 16 + l16] = __float2bfloat16(s[nt][r]);
    __syncthreads();

    // O += P @ V
    short8 ap[2];
#pragma unroll
    for (int kk = 0; kk < 2; kk++)
      ap[kk] = *(const short8*)&Ps[wave][l16][kk * 32 + quad * 8];
#pragma unroll
    for (int vt = 0; vt < 8; vt++) {
      f32x4 a = o[vt];
#pragma unroll
      for (int kk = 0; kk < 2; kk++) {
        short8 bv = *(const short8*)&Vt[vt * 16 + l16][kk * 32 + quad * 8];
        a = __builtin_amdgcn_mfma_f32_16x16x32_bf16(ap[kk], bv, a, 0, 0, 0);
      }
      o[vt] = a;
    }
    __syncthreads();
  }

  // epilogue: attnb[(b*2048+t)*2048 + h*128 + d]
#pragma unroll
  for (int r = 0; r < 4; r++) {
    float inv = 1.0f / l_i[r];
    int trow = q0 + wave * 16 + quad * 4 + r;
    size_t base = ((size_t)b * 2048 + trow) * 2048 + h * 128;
#pragma unroll
    for (int vt = 0; vt < 8; vt++)
      attnb[base + vt * 16 + l16] = __float2bfloat16(o[vt][r] * inv);
  }
}

__global__ void finalize(float* out) {
  if (threadIdx.x == 0 && blockIdx.x == 0) out[(size_t)8192 * 2048] = 0.0f;
}

extern "C" void kernel_launch(void* const* d_in, const int* in_sizes, int n_in,
                              void* d_out, int out_size, void* d_ws, size_t ws_size,
                              hipStream_t stream) {
  const float* x  = (const float*)d_in[0];
  const float* Wq = (const float*)d_in[1];
  const float* Wk = (const float*)d_in[2];
  const float* Wv = (const float*)d_in[3];
  const float* Wo = (const float*)d_in[4];
  float* out = (float*)d_out;

  char* ws = (char*)d_ws;
  __hip_bfloat16* xb    = (__hip_bfloat16*)(ws);               // 8192x2048  (33.5MB)
  __hip_bfloat16* wqkv  = (__hip_bfloat16*)(ws + 33554432);    // 3072x2048  (12.6MB)
  __hip_bfloat16* wob   = (__hip_bfloat16*)(ws + 46137344);    // 2048x2048  (8.4MB)
  __hip_bfloat16* qkvb  = (__hip_bfloat16*)(ws + 54525952);    // 8192x3072  (50.3MB)
  __hip_bfloat16* qb    = (__hip_bfloat16*)(ws + 104857600);   // (b,h,t,d)  (33.5MB)
  __hip_bfloat16* kb    = (__hip_bfloat16*)(ws + 138412032);   // (b,hkv,t,d) (8.4MB)
  __hip_bfloat16* vb    = (__hip_bfloat16*)(ws + 146800640);   // (b,hkv,t,d) (8.4MB)
  __hip_bfloat16* attnb = qkvb;  // alias: qkv dead after norm_rope

  cast_f32_bf16<<<16384, 256, 0, stream>>>((const float4*)x,  (unsigned long long*)xb, 4194304);
  cast_f32_bf16<<<4096,  256, 0, stream>>>((const float4*)Wq, (unsigned long long*)wqkv, 1048576);
  cast_f32_bf16<<<1024,  256, 0, stream>>>((const float4*)Wk, (unsigned long long*)(wqkv + 2048 * 2048), 262144);
  cast_f32_bf16<<<1024,  256, 0, stream>>>((const float4*)Wv, (unsigned long long*)(wqkv + 2560 * 2048), 262144);
  cast_f32_bf16<<<4096,  256, 0, stream>>>((const float4*)Wo, (unsigned long long*)wob, 1048576);

  gemm_bt<__hip_bfloat16><<<dim3(24, 64), 256, 0, stream>>>(xb, wqkv, qkvb, 8192, 3072, 2048);
  norm_rope<<<dim3(24, 8192), 128, 0, stream>>>(qkvb, qb, kb, vb);
  flash_attn<<<dim3(32, 64), 256, 0, stream>>>(qb, kb, vb, attnb);
  gemm_bt<float><<<dim3(16, 64), 256, 0, stream>>>(attnb, wob, out, 8192, 2048, 2048);
  finalize<<<1, 64, 0, stream>>>(out);
}

// Round 2
// 916.572 us; speedup vs baseline: 1.3262x; 1.3262x over previous
//
#include <hip/hip_runtime.h>
#include <hip/hip_bf16.h>

typedef __attribute__((ext_vector_type(8))) short short8;
typedef __attribute__((ext_vector_type(4))) float f32x4;
using bf16 = __hip_bfloat16;

__device__ inline unsigned short f2bfu(float x) {
  bf16 h = __float2bfloat16(x);
  return __builtin_bit_cast(unsigned short, h);
}

// async global->LDS 16B copy (lands at wave-uniform base + lane*16)
__device__ __forceinline__ void gll16(const void* g, void* l) {
  __builtin_amdgcn_global_load_lds(
      (const __attribute__((address_space(1))) unsigned int*)g,
      (__attribute__((address_space(3))) unsigned int*)l, 16, 0, 0);
}

// ---------------- cast fp32 -> bf16, 4 elems/thread ----------------
__global__ __launch_bounds__(256) void cast_f32_bf16(const float4* __restrict__ src,
                                                     unsigned long long* __restrict__ dst,
                                                     int n4) {
  int i = blockIdx.x * 256 + threadIdx.x;
  if (i >= n4) return;
  float4 v = src[i];
  unsigned long long r = (unsigned long long)f2bfu(v.x)
                       | ((unsigned long long)f2bfu(v.y) << 16)
                       | ((unsigned long long)f2bfu(v.z) << 32)
                       | ((unsigned long long)f2bfu(v.w) << 48);
  dst[i] = r;
}

// ---------------- GEMM: C[M,N] = A[M,K] * B[N,K]^T (m97-style async staging) ----------------
__device__ inline void store_cvt(float* p, float v) { *p = v; }
__device__ inline void store_cvt(bf16* p, float v) { *p = __float2bfloat16(v); }

template <typename OutT>
__global__ __launch_bounds__(256) void gemm_bt(const bf16* __restrict__ A,
                                               const bf16* __restrict__ B,
                                               OutT* __restrict__ C,
                                               int M, int N, int K) {
  __shared__ __align__(16) bf16 As[128][32];   // unpadded: required by global_load_lds
  __shared__ __align__(16) bf16 Bs[128][32];
  const int tid = threadIdx.x;
  const int wave = tid >> 6, lane = tid & 63;
  const int wm = wave >> 1, wn = wave & 1;
  const int quad = lane >> 4, l16 = lane & 15;
  const int m0 = blockIdx.y * 128, n0 = blockIdx.x * 128;
  const int c0 = tid, c1 = tid + 256;          // chunk ids; LDS elem offset = chunk*8
  const int r0 = c0 >> 2, k0 = (c0 & 3) * 8;
  const int r1 = c1 >> 2, k1 = (c1 & 3) * 8;
  f32x4 acc[4][4] = {};
  for (int kt = 0; kt < K; kt += 32) {
    gll16(&A[(size_t)(m0 + r0) * K + kt + k0], (bf16*)As + (size_t)c0 * 8);
    gll16(&A[(size_t)(m0 + r1) * K + kt + k1], (bf16*)As + (size_t)c1 * 8);
    gll16(&B[(size_t)(n0 + r0) * K + kt + k0], (bf16*)Bs + (size_t)c0 * 8);
    gll16(&B[(size_t)(n0 + r1) * K + kt + k1], (bf16*)Bs + (size_t)c1 * 8);
    __syncthreads();   // compiler drains vmcnt(0) here
    short8 af[4], bfr[4];
#pragma unroll
    for (int t = 0; t < 4; t++) {
      af[t]  = *(const short8*)&As[wm * 64 + t * 16 + l16][quad * 8];
      bfr[t] = *(const short8*)&Bs[wn * 64 + t * 16 + l16][quad * 8];
    }
#pragma unroll
    for (int im = 0; im < 4; im++)
#pragma unroll
      for (int in = 0; in < 4; in++)
        acc[im][in] = __builtin_amdgcn_mfma_f32_16x16x32_bf16(af[im], bfr[in], acc[im][in], 0, 0, 0);
    __syncthreads();
  }
#pragma unroll
  for (int im = 0; im < 4; im++)
#pragma unroll
    for (int in = 0; in < 4; in++) {
      int col = n0 + wn * 64 + in * 16 + l16;
#pragma unroll
      for (int r = 0; r < 4; r++) {
        int row = m0 + wm * 64 + im * 16 + quad * 4 + r;
        store_cvt(&C[(size_t)row * N + col], acc[im][in][r]);
      }
    }
}

// ---------------- RMSNorm + RoPE ----------------
// qkv: [8192][3072]. slots 0..15 q (scaled by 1/sqrt(D)), 16..19 k, 20..23 v.
__global__ __launch_bounds__(128) void norm_rope(const bf16* __restrict__ qkv,
                                                 bf16* __restrict__ qb,
                                                 bf16* __restrict__ kb,
                                                 bf16* __restrict__ vb) {
  const int token = blockIdx.y;
  const int slot = blockIdx.x;
  const int d = threadIdx.x;
  const int b = token >> 11, t = token & 2047;
  float val = __bfloat162float(qkv[(size_t)token * 3072 + slot * 128 + d]);
  if (slot >= 20) {
    vb[(((size_t)(b * 4 + (slot - 20))) * 2048 + t) * 128 + d] = __float2bfloat16(val);
    return;
  }
  float ss = val * val;
#pragma unroll
  for (int m = 1; m < 64; m <<= 1) ss += __shfl_xor(ss, m, 64);
  __shared__ float red[2];
  __shared__ float rowv[128];
  if ((threadIdx.x & 63) == 0) red[threadIdx.x >> 6] = ss;
  __syncthreads();
  float rinv = rsqrtf((red[0] + red[1]) * (1.0f / 128.0f) + 1.1920929e-7f);
  rowv[d] = val * rinv;
  __syncthreads();
  int i = d & 63;
  float x1 = rowv[i], x2 = rowv[i + 64];
  float inv_freq = expf(-(float)i * (9.210340371976184f / 64.0f));
  float ph = (float)t * inv_freq;
  float c = cosf(ph), s = sinf(ph);
  float outv = (d < 64) ? (x1 * c + x2 * s) : (x2 * c - x1 * s);
  if (slot < 16) {
    outv *= 0.08838834764831845f;  // fold 1/sqrt(D) into q
    qb[(((size_t)(b * 16 + slot)) * 2048 + t) * 128 + d] = __float2bfloat16(outv);
  } else {
    kb[(((size_t)(b * 4 + (slot - 16))) * 2048 + t) * 128 + d] = __float2bfloat16(outv);
  }
}

// ---------------- V transpose: (s, t, d) -> (s, d, t), s = b*4+hkv (16 slices) ----------------
__global__ __launch_bounds__(256) void transpose_v(const bf16* __restrict__ vin,
                                                   bf16* __restrict__ vout) {
  __shared__ __align__(16) bf16 til[64][144];
  const int tid = threadIdx.x;
  const bf16* src = vin + ((size_t)blockIdx.y * 2048 + blockIdx.x * 64) * 128;
  bf16* dst = vout + (size_t)blockIdx.y * 128 * 2048 + blockIdx.x * 64;
#pragma unroll
  for (int p = 0; p < 4; p++) {
    int idx = p * 256 + tid;
    *(uint4*)&til[idx >> 4][(idx & 15) * 8] = *(const uint4*)&src[(size_t)(idx >> 4) * 128 + (idx & 15) * 8];
  }
  __syncthreads();
  const int ds = tid & 127;   // output row (d); lane-consecutive => conflict-free LDS reads
  const int hs = tid >> 7;
#pragma unroll
  for (int p = 0; p < 4; p++) {
    int c8 = (p * 2 + hs) * 8;
    short8 v;
#pragma unroll
    for (int j = 0; j < 8; j++) v[j] = *(const short*)&til[c8 + j][ds];
    *(short8*)&dst[(size_t)ds * 2048 + c8] = v;
  }
}

// ---------------- causal GQA flash attention ----------------
// grid (16, 64): 128 Q-rows/block, 4 waves x 32 rows. Q in registers.
// qb (b,h,t,d); kb (b,hkv,t,d); vtg (b,hkv,d,t); attnb (b,t,h*128+d)
__global__ __launch_bounds__(256, 3) void flash_attn(const bf16* __restrict__ qb,
                                                     const bf16* __restrict__ kb,
                                                     const bf16* __restrict__ vtg,
                                                     bf16* __restrict__ attnb) {
  const int qt = gridDim.x - 1 - blockIdx.x;  // heavy blocks first
  const int bh = blockIdx.y;
  const int b = bh >> 4, h = bh & 15, hkv = h >> 2;
  const int q0 = qt * 128;
  const bf16* Q  = qb  + ((size_t)(b * 16 + h) * 2048 + q0) * 128;
  const bf16* Kp = kb  + (size_t)(b * 4 + hkv) * 2048 * 128;
  const bf16* Vg = vtg + (size_t)(b * 4 + hkv) * 128 * 2048;

  __shared__ __align__(16) bf16 Ks[64][136];    // 17.4 KB
  __shared__ __align__(16) bf16 Vt[128][72];    // 18.4 KB  [d][t]
  __shared__ __align__(16) bf16 Ps[4][32][72];  // 18.4 KB  per-wave slab

  const int tid = threadIdx.x;
  const int w = tid >> 6, lane = tid & 63;
  const int quad = lane >> 4, l16 = lane & 15;
  const int qw = q0 + w * 32;

  // Q fragments in registers (A-layout), already scaled by 1/sqrt(D)
  short8 aq[2][4];
#pragma unroll
  for (int mi = 0; mi < 2; mi++)
#pragma unroll
    for (int dk = 0; dk < 4; dk++)
      aq[mi][dk] = *(const short8*)&Q[(size_t)(w * 32 + mi * 16 + l16) * 128 + dk * 32 + quad * 8];

  f32x4 o[2][8] = {};
  float m_i[2][4], l_i[2][4];
#pragma unroll
  for (int mi = 0; mi < 2; mi++)
#pragma unroll
    for (int r = 0; r < 4; r++) { m_i[mi][r] = -1e30f; l_i[mi][r] = 0.f; }

  const int ntiles = 2 * qt + 2;
  const int wmax = qw + 31;
  for (int kt = 0; kt < ntiles; kt++) {
    const int kv0 = kt * 64;
    // stage K row-major, V already d-major (both vectorized 16B)
#pragma unroll
    for (int p = 0; p < 4; p++) {
      int idx = p * 256 + tid;
      *(uint4*)&Ks[idx >> 4][(idx & 15) * 8] =
          *(const uint4*)&Kp[(size_t)(kv0 + (idx >> 4)) * 128 + (idx & 15) * 8];
    }
#pragma unroll
    for (int p = 0; p < 4; p++) {
      int idx = p * 256 + tid;
      *(uint4*)&Vt[idx >> 3][(idx & 7) * 8] =
          *(const uint4*)&Vg[(size_t)(idx >> 3) * 2048 + kv0 + (idx & 7) * 8];
    }
    __syncthreads();

    if (kv0 <= wmax) {  // wave-uniform causal skip
      // S = Q K^T : 2 m-frags share each K fragment read
      f32x4 s[2][4] = {};
#pragma unroll
      for (int nt = 0; nt < 4; nt++)
#pragma unroll
        for (int dk = 0; dk < 4; dk++) {
          short8 bk = *(const short8*)&Ks[nt * 16 + l16][dk * 32 + quad * 8];
          s[0][nt] = __builtin_amdgcn_mfma_f32_16x16x32_bf16(aq[0][dk], bk, s[0][nt], 0, 0, 0);
          s[1][nt] = __builtin_amdgcn_mfma_f32_16x16x32_bf16(aq[1][dk], bk, s[1][nt], 0, 0, 0);
        }

#pragma unroll
      for (int mi = 0; mi < 2; mi++) {
        const int fr0 = qw + mi * 16;
        float mt[4] = {-1e30f, -1e30f, -1e30f, -1e30f};
        if (kv0 + 63 > fr0) {  // diagonal tile: mask
#pragma unroll
          for (int nt = 0; nt < 4; nt++)
#pragma unroll
            for (int r = 0; r < 4; r++) {
              float x = s[mi][nt][r];
              int qrow = fr0 + quad * 4 + r;
              int kcol = kv0 + nt * 16 + l16;
              if (kcol > qrow) x = -1e30f;
              s[mi][nt][r] = x;
              mt[r] = fmaxf(mt[r], x);
            }
        } else {
#pragma unroll
          for (int nt = 0; nt < 4; nt++)
#pragma unroll
            for (int r = 0; r < 4; r++) mt[r] = fmaxf(mt[r], s[mi][nt][r]);
        }
#pragma unroll
        for (int r = 0; r < 4; r++) {
#pragma unroll
          for (int mm = 1; mm < 16; mm <<= 1) mt[r] = fmaxf(mt[r], __shfl_xor(mt[r], mm, 64));
        }
        float alpha[4], rowsum[4];
#pragma unroll
        for (int r = 0; r < 4; r++) {
          float mn = fmaxf(m_i[mi][r], mt[r]);
          alpha[r] = __expf(m_i[mi][r] - mn);
          m_i[mi][r] = mn;
          rowsum[r] = 0.f;
        }
#pragma unroll
        for (int nt = 0; nt < 4; nt++)
#pragma unroll
          for (int r = 0; r < 4; r++) {
            float p = __expf(s[mi][nt][r] - m_i[mi][r]);
            rowsum[r] += p;
            Ps[w][mi * 16 + quad * 4 + r][nt * 16 + l16] = __float2bfloat16(p);
          }
#pragma unroll
        for (int r = 0; r < 4; r++) {
#pragma unroll
          for (int mm = 1; mm < 16; mm <<= 1) rowsum[r] += __shfl_xor(rowsum[r], mm, 64);
          l_i[mi][r] = l_i[mi][r] * alpha[r] + rowsum[r];
        }
#pragma unroll
        for (int vt = 0; vt < 8; vt++)
#pragma unroll
          for (int r = 0; r < 4; r++) o[mi][vt][r] *= alpha[r];
      }
      __threadfence_block();  // intra-wave RAW on Ps (per-wave slab, no barrier needed)

      // O += P @ V
      short8 ap[2][2];
#pragma unroll
      for (int mi = 0; mi < 2; mi++)
#pragma unroll
        for (int kk = 0; kk < 2; kk++)
          ap[mi][kk] = *(const short8*)&Ps[w][mi * 16 + l16][kk * 32 + quad * 8];
#pragma unroll
      for (int vt = 0; vt < 8; vt++)
#pragma unroll
        for (int kk = 0; kk < 2; kk++) {
          short8 bv = *(const short8*)&Vt[vt * 16 + l16][kk * 32 + quad * 8];
          o[0][vt] = __builtin_amdgcn_mfma_f32_16x16x32_bf16(ap[0][kk], bv, o[0][vt], 0, 0, 0);
          o[1][vt] = __builtin_amdgcn_mfma_f32_16x16x32_bf16(ap[1][kk], bv, o[1][vt], 0, 0, 0);
        }
    }
    __syncthreads();
  }

#pragma unroll
  for (int mi = 0; mi < 2; mi++)
#pragma unroll
    for (int r = 0; r < 4; r++) {
      float inv = 1.0f / l_i[mi][r];
      int trow = qw + mi * 16 + quad * 4 + r;
      size_t base = ((size_t)b * 2048 + trow) * 2048 + h * 128;
#pragma unroll
      for (int vt = 0; vt < 8; vt++)
        attnb[base + vt * 16 + l16] = __float2bfloat16(o[mi][vt][r] * inv);
    }
}

__global__ void finalize(float* out) {
  if (threadIdx.x == 0 && blockIdx.x == 0) out[(size_t)8192 * 2048] = 0.0f;
}

extern "C" void kernel_launch(void* const* d_in, const int* in_sizes, int n_in,
                              void* d_out, int out_size, void* d_ws, size_t ws_size,
                              hipStream_t stream) {
  const float* x  = (const float*)d_in[0];
  const float* Wq = (const float*)d_in[1];
  const float* Wk = (const float*)d_in[2];
  const float* Wv = (const float*)d_in[3];
  const float* Wo = (const float*)d_in[4];
  float* out = (float*)d_out;

  char* ws = (char*)d_ws;
  bf16* xb    = (bf16*)(ws);               // 33.5 MB
  bf16* wqkv  = (bf16*)(ws + 33554432);    // 12.6 MB (dead after QKV gemm)
  bf16* vtb   = (bf16*)(ws + 33554432);    // 8.4 MB, aliases wqkv
  bf16* wob   = (bf16*)(ws + 46137344);    // 8.4 MB
  bf16* qkvb  = (bf16*)(ws + 54525952);    // 50.3 MB
  bf16* qb    = (bf16*)(ws + 104857600);   // 33.5 MB
  bf16* kb    = (bf16*)(ws + 138412032);   // 8.4 MB
  bf16* vb    = (bf16*)(ws + 146800640);   // 8.4 MB
  bf16* attnb = qkvb;                      // alias: qkv dead after norm_rope

  cast_f32_bf16<<<16384, 256, 0, stream>>>((const float4*)x,  (unsigned long long*)xb, 4194304);
  cast_f32_bf16<<<4096,  256, 0, stream>>>((const float4*)Wq, (unsigned long long*)wqkv, 1048576);
  cast_f32_bf16<<<1024,  256, 0, stream>>>((const float4*)Wk, (unsigned long long*)(wqkv + 2048 * 2048), 262144);
  cast_f32_bf16<<<1024,  256, 0, stream>>>((const float4*)Wv, (unsigned long long*)(wqkv + 2560 * 2048), 262144);
  cast_f32_bf16<<<4096,  256, 0, stream>>>((const float4*)Wo, (unsigned long long*)wob, 1048576);

  gemm_bt<bf16><<<dim3(24, 64), 256, 0, stream>>>(xb, wqkv, qkvb, 8192, 3072, 2048);
  norm_rope<<<dim3(24, 8192), 128, 0, stream>>>(qkvb, qb, kb, vb);
  transpose_v<<<dim3(32, 16), 256, 0, stream>>>(vb, vtb);
  flash_attn<<<dim3(16, 64), 256, 0, stream>>>(qb, kb, vtb, attnb);
  gemm_bt<float><<<dim3(16, 64), 256, 0, stream>>>(attnb, wob, out, 8192, 2048, 2048);
  finalize<<<1, 64, 0, stream>>>(out);
}

// Round 3
// 628.429 us; speedup vs baseline: 1.9343x; 1.4585x over previous
//
#include <hip/hip_runtime.h>
#include <hip/hip_bf16.h>

typedef __attribute__((ext_vector_type(8))) short short8;
typedef __attribute__((ext_vector_type(4))) float f32x4;
using bf16 = __hip_bfloat16;

__device__ inline unsigned short f2bfu(float x) {
  bf16 h = __float2bfloat16(x);
  return __builtin_bit_cast(unsigned short, h);
}

// async global->LDS 16B copy (lands at wave-uniform base + lane*16)
__device__ __forceinline__ void gll16(const void* g, void* l) {
  __builtin_amdgcn_global_load_lds(
      (const __attribute__((address_space(1))) unsigned int*)g,
      (__attribute__((address_space(3))) unsigned int*)l, 16, 0, 0);
}

// ---------------- cast fp32 -> bf16, 4 elems/thread ----------------
__global__ __launch_bounds__(256) void cast_f32_bf16(const float4* __restrict__ src,
                                                     unsigned long long* __restrict__ dst,
                                                     int n4) {
  int i = blockIdx.x * 256 + threadIdx.x;
  if (i >= n4) return;
  float4 v = src[i];
  unsigned long long r = (unsigned long long)f2bfu(v.x)
                       | ((unsigned long long)f2bfu(v.y) << 16)
                       | ((unsigned long long)f2bfu(v.z) << 32)
                       | ((unsigned long long)f2bfu(v.w) << 48);
  dst[i] = r;
}

// ---------------- GEMM: C[M,N] = A[M,K] * B[N,K]^T (m97-style async staging) ----------------
__device__ inline void store_cvt(float* p, float v) { *p = v; }
__device__ inline void store_cvt(bf16* p, float v) { *p = __float2bfloat16(v); }

template <typename OutT>
__global__ __launch_bounds__(256) void gemm_bt(const bf16* __restrict__ A,
                                               const bf16* __restrict__ B,
                                               OutT* __restrict__ C,
                                               int M, int N, int K) {
  __shared__ __align__(16) bf16 As[128][32];   // unpadded: required by global_load_lds
  __shared__ __align__(16) bf16 Bs[128][32];
  const int tid = threadIdx.x;
  const int wave = tid >> 6, lane = tid & 63;
  const int wm = wave >> 1, wn = wave & 1;
  const int quad = lane >> 4, l16 = lane & 15;
  const int m0 = blockIdx.y * 128, n0 = blockIdx.x * 128;
  const int c0 = tid, c1 = tid + 256;
  const int r0 = c0 >> 2, k0 = (c0 & 3) * 8;
  const int r1 = c1 >> 2, k1 = (c1 & 3) * 8;
  f32x4 acc[4][4] = {};
  for (int kt = 0; kt < K; kt += 32) {
    gll16(&A[(size_t)(m0 + r0) * K + kt + k0], (bf16*)As + (size_t)c0 * 8);
    gll16(&A[(size_t)(m0 + r1) * K + kt + k1], (bf16*)As + (size_t)c1 * 8);
    gll16(&B[(size_t)(n0 + r0) * K + kt + k0], (bf16*)Bs + (size_t)c0 * 8);
    gll16(&B[(size_t)(n0 + r1) * K + kt + k1], (bf16*)Bs + (size_t)c1 * 8);
    __syncthreads();
    short8 af[4], bfr[4];
#pragma unroll
    for (int t = 0; t < 4; t++) {
      af[t]  = *(const short8*)&As[wm * 64 + t * 16 + l16][quad * 8];
      bfr[t] = *(const short8*)&Bs[wn * 64 + t * 16 + l16][quad * 8];
    }
#pragma unroll
    for (int im = 0; im < 4; im++)
#pragma unroll
      for (int in = 0; in < 4; in++)
        acc[im][in] = __builtin_amdgcn_mfma_f32_16x16x32_bf16(af[im], bfr[in], acc[im][in], 0, 0, 0);
    __syncthreads();
  }
#pragma unroll
  for (int im = 0; im < 4; im++)
#pragma unroll
    for (int in = 0; in < 4; in++) {
      int col = n0 + wn * 64 + in * 16 + l16;
#pragma unroll
      for (int r = 0; r < 4; r++) {
        int row = m0 + wm * 64 + im * 16 + quad * 4 + r;
        store_cvt(&C[(size_t)row * N + col], acc[im][in][r]);
      }
    }
}

// ---------------- RMSNorm + RoPE ----------------
__global__ __launch_bounds__(128) void norm_rope(const bf16* __restrict__ qkv,
                                                 bf16* __restrict__ qb,
                                                 bf16* __restrict__ kb,
                                                 bf16* __restrict__ vb) {
  const int token = blockIdx.y;
  const int slot = blockIdx.x;
  const int d = threadIdx.x;
  const int b = token >> 11, t = token & 2047;
  float val = __bfloat162float(qkv[(size_t)token * 3072 + slot * 128 + d]);
  if (slot >= 20) {
    vb[(((size_t)(b * 4 + (slot - 20))) * 2048 + t) * 128 + d] = __float2bfloat16(val);
    return;
  }
  float ss = val * val;
#pragma unroll
  for (int m = 1; m < 64; m <<= 1) ss += __shfl_xor(ss, m, 64);
  __shared__ float red[2];
  __shared__ float rowv[128];
  if ((threadIdx.x & 63) == 0) red[threadIdx.x >> 6] = ss;
  __syncthreads();
  float rinv = rsqrtf((red[0] + red[1]) * (1.0f / 128.0f) + 1.1920929e-7f);
  rowv[d] = val * rinv;
  __syncthreads();
  int i = d & 63;
  float x1 = rowv[i], x2 = rowv[i + 64];
  float inv_freq = __expf(-(float)i * (9.210340371976184f / 64.0f));
  float ph = (float)t * inv_freq;
  float c, s;
  __sincosf(ph, &s, &c);
  float outv = (d < 64) ? (x1 * c + x2 * s) : (x2 * c - x1 * s);
  if (slot < 16) {
    outv *= 0.08838834764831845f;  // fold 1/sqrt(D) into q
    qb[(((size_t)(b * 16 + slot)) * 2048 + t) * 128 + d] = __float2bfloat16(outv);
  } else {
    kb[(((size_t)(b * 4 + (slot - 16))) * 2048 + t) * 128 + d] = __float2bfloat16(outv);
  }
}

// ---------------- V transpose: (s, t, d) -> (s, d, t) ----------------
__global__ __launch_bounds__(256) void transpose_v(const bf16* __restrict__ vin,
                                                   bf16* __restrict__ vout) {
  __shared__ __align__(16) bf16 til[64][144];
  const int tid = threadIdx.x;
  const bf16* src = vin + ((size_t)blockIdx.y * 2048 + blockIdx.x * 64) * 128;
  bf16* dst = vout + (size_t)blockIdx.y * 128 * 2048 + blockIdx.x * 64;
#pragma unroll
  for (int p = 0; p < 4; p++) {
    int idx = p * 256 + tid;
    *(uint4*)&til[idx >> 4][(idx & 15) * 8] = *(const uint4*)&src[(size_t)(idx >> 4) * 128 + (idx & 15) * 8];
  }
  __syncthreads();
  const int ds = tid & 127;
  const int hs = tid >> 7;
#pragma unroll
  for (int p = 0; p < 4; p++) {
    int c8 = (p * 2 + hs) * 8;
    short8 v;
#pragma unroll
    for (int j = 0; j < 8; j++) v[j] = *(const short*)&til[c8 + j][ds];
    *(short8*)&dst[(size_t)ds * 2048 + c8] = v;
  }
}

// ---------------- causal GQA flash attention ----------------
// grid (16, 64), 512 threads = 8 waves x 16 Q-rows. Fixed-shift softmax (no online max):
// RMS-normed q,k => |s| <= sqrt(128) < 12, so p = exp(s-12) <= 1, rowsum <= 2048.
// Register-prefetched K/V staging; prefetch issued after barrier so it overlaps compute.
__global__ __launch_bounds__(512, 4) void flash_attn(const bf16* __restrict__ qb,
                                                     const bf16* __restrict__ kb,
                                                     const bf16* __restrict__ vtg,
                                                     bf16* __restrict__ attnb) {
  const int qt = gridDim.x - 1 - blockIdx.x;  // heavy blocks first
  const int bh = blockIdx.y;
  const int b = bh >> 4, h = bh & 15, hkv = h >> 2;
  const int q0 = qt * 128;
  const bf16* Q  = qb  + ((size_t)(b * 16 + h) * 2048 + q0) * 128;
  const bf16* Kp = kb  + (size_t)(b * 4 + hkv) * 2048 * 128;
  const bf16* Vg = vtg + (size_t)(b * 4 + hkv) * 128 * 2048;

  __shared__ __align__(16) bf16 Ks[64][136];    // 17.4 KB
  __shared__ __align__(16) bf16 Vt[128][72];    // 18.4 KB  [d][t]
  __shared__ __align__(16) bf16 Ps[8][16][72];  // 18.4 KB  per-wave slab

  const int tid = threadIdx.x;
  const int w = tid >> 6, lane = tid & 63;
  const int quad = lane >> 4, l16 = lane & 15;
  const int qw = q0 + w * 16;

  // staging coords (512 threads, 2 chunks each for K and V)
  const int krow = tid >> 4, kc8 = (tid & 15) * 8;
  const int vrow = tid >> 3, vc8 = (tid & 7) * 8;

  // Q fragments in registers (A-layout), pre-scaled by 1/sqrt(D)
  short8 aq[4];
#pragma unroll
  for (int dk = 0; dk < 4; dk++)
    aq[dk] = *(const short8*)&Q[(size_t)(w * 16 + l16) * 128 + dk * 32 + quad * 8];

  f32x4 o[8] = {};
  float l_i[4] = {0.f, 0.f, 0.f, 0.f};

  const int ntiles = 2 * qt + 2;
  // preload tile 0 into regs
  uint4 ka0 = *(const uint4*)&Kp[(size_t)krow * 128 + kc8];
  uint4 ka1 = *(const uint4*)&Kp[(size_t)(krow + 32) * 128 + kc8];
  uint4 va0 = *(const uint4*)&Vg[(size_t)vrow * 2048 + vc8];
  uint4 va1 = *(const uint4*)&Vg[(size_t)(vrow + 64) * 2048 + vc8];

  for (int kt = 0; kt < ntiles; kt++) {
    const int kv0 = kt * 64;
    // write prefetched regs to LDS (vmcnt wait here is free: loads issued a full tile ago)
    *(uint4*)&Ks[krow][kc8]      = ka0;
    *(uint4*)&Ks[krow + 32][kc8] = ka1;
    *(uint4*)&Vt[vrow][vc8]      = va0;
    *(uint4*)&Vt[vrow + 64][vc8] = va1;
    __syncthreads();

    // issue prefetch for next tile NOW so it flies during compute
    const int nkv0 = min(kv0 + 64, (ntiles - 1) * 64);
    ka0 = *(const uint4*)&Kp[(size_t)(nkv0 + krow) * 128 + kc8];
    ka1 = *(const uint4*)&Kp[(size_t)(nkv0 + krow + 32) * 128 + kc8];
    va0 = *(const uint4*)&Vg[(size_t)vrow * 2048 + nkv0 + vc8];
    va1 = *(const uint4*)&Vg[(size_t)(vrow + 64) * 2048 + nkv0 + vc8];

    if (kv0 <= qw + 15) {  // wave-uniform causal skip
      // S = Q K^T (16 rows x 64 cols)
      f32x4 s[4] = {};
#pragma unroll
      for (int nt = 0; nt < 4; nt++)
#pragma unroll
        for (int dk = 0; dk < 4; dk++) {
          short8 bk = *(const short8*)&Ks[nt * 16 + l16][dk * 32 + quad * 8];
          s[nt] = __builtin_amdgcn_mfma_f32_16x16x32_bf16(aq[dk], bk, s[nt], 0, 0, 0);
        }

      // fixed-shift softmax: p = exp(s - 12); no cross-lane ops
      const bool dtile = (kv0 + 63 > qw);
      const int qrow = qw + quad * 4;  // + r
#pragma unroll
      for (int nt = 0; nt < 4; nt++) {
        const int kcol = kv0 + nt * 16 + l16;
#pragma unroll
        for (int r = 0; r < 4; r++) {
          float p = __expf(s[nt][r] - 12.0f);
          if (dtile && kcol > qrow + r) p = 0.f;
          l_i[r] += p;
          Ps[w][quad * 4 + r][nt * 16 + l16] = __float2bfloat16(p);
        }
      }
      __threadfence_block();  // intra-wave RAW on per-wave Ps slab

      // O += P @ V
      short8 ap[2];
#pragma unroll
      for (int kk = 0; kk < 2; kk++)
        ap[kk] = *(const short8*)&Ps[w][l16][kk * 32 + quad * 8];
#pragma unroll
      for (int vt = 0; vt < 8; vt++)
#pragma unroll
        for (int kk = 0; kk < 2; kk++) {
          short8 bv = *(const short8*)&Vt[vt * 16 + l16][kk * 32 + quad * 8];
          o[vt] = __builtin_amdgcn_mfma_f32_16x16x32_bf16(ap[kk], bv, o[vt], 0, 0, 0);
        }
    }
    __syncthreads();  // drains prefetch vmcnt too — free, compute >> latency
  }

  // epilogue: single cross-lane l reduction (16 lanes share a row's partials)
#pragma unroll
  for (int r = 0; r < 4; r++) {
#pragma unroll
    for (int mm = 1; mm < 16; mm <<= 1) l_i[r] += __shfl_xor(l_i[r], mm, 64);
  }
#pragma unroll
  for (int r = 0; r < 4; r++) {
    float inv = 1.0f / l_i[r];
    int trow = qw + quad * 4 + r;
    size_t base = ((size_t)b * 2048 + trow) * 2048 + h * 128;
#pragma unroll
    for (int vt = 0; vt < 8; vt++)
      attnb[base + vt * 16 + l16] = __float2bfloat16(o[vt][r] * inv);
  }
}

__global__ void finalize(float* out) {
  if (threadIdx.x == 0 && blockIdx.x == 0) out[(size_t)8192 * 2048] = 0.0f;
}

extern "C" void kernel_launch(void* const* d_in, const int* in_sizes, int n_in,
                              void* d_out, int out_size, void* d_ws, size_t ws_size,
                              hipStream_t stream) {
  const float* x  = (const float*)d_in[0];
  const float* Wq = (const float*)d_in[1];
  const float* Wk = (const float*)d_in[2];
  const float* Wv = (const float*)d_in[3];
  const float* Wo = (const float*)d_in[4];
  float* out = (float*)d_out;

  char* ws = (char*)d_ws;
  bf16* xb    = (bf16*)(ws);               // 33.5 MB
  bf16* wqkv  = (bf16*)(ws + 33554432);    // 12.6 MB (dead after QKV gemm)
  bf16* vtb   = (bf16*)(ws + 33554432);    // 8.4 MB, aliases wqkv
  bf16* wob   = (bf16*)(ws + 46137344);    // 8.4 MB
  bf16* qkvb  = (bf16*)(ws + 54525952);    // 50.3 MB
  bf16* qb    = (bf16*)(ws + 104857600);   // 33.5 MB
  bf16* kb    = (bf16*)(ws + 138412032);   // 8.4 MB
  bf16* vb    = (bf16*)(ws + 146800640);   // 8.4 MB
  bf16* attnb = qkvb;                      // alias: qkv dead after norm_rope

  cast_f32_bf16<<<16384, 256, 0, stream>>>((const float4*)x,  (unsigned long long*)xb, 4194304);
  cast_f32_bf16<<<4096,  256, 0, stream>>>((const float4*)Wq, (unsigned long long*)wqkv, 1048576);
  cast_f32_bf16<<<1024,  256, 0, stream>>>((const float4*)Wk, (unsigned long long*)(wqkv + 2048 * 2048), 262144);
  cast_f32_bf16<<<1024,  256, 0, stream>>>((const float4*)Wv, (unsigned long long*)(wqkv + 2560 * 2048), 262144);
  cast_f32_bf16<<<4096,  256, 0, stream>>>((const float4*)Wo, (unsigned long long*)wob, 1048576);

  gemm_bt<bf16><<<dim3(24, 64), 256, 0, stream>>>(xb, wqkv, qkvb, 8192, 3072, 2048);
  norm_rope<<<dim3(24, 8192), 128, 0, stream>>>(qkvb, qb, kb, vb);
  transpose_v<<<dim3(32, 16), 256, 0, stream>>>(vb, vtb);
  flash_attn<<<dim3(16, 64), 512, 0, stream>>>(qb, kb, vtb, attnb);
  gemm_bt<float><<<dim3(16, 64), 256, 0, stream>>>(attnb, wob, out, 8192, 2048, 2048);
  finalize<<<1, 64, 0, stream>>>(out);
}

// Round 4
// 537.931 us; speedup vs baseline: 2.2597x; 1.1682x over previous
//
#include <hip/hip_runtime.h>
#include <hip/hip_bf16.h>

typedef __attribute__((ext_vector_type(8))) short short8;
typedef __attribute__((ext_vector_type(4))) float f32x4;
using bf16 = __hip_bfloat16;

__device__ inline unsigned short f2bfu(float x) {
  bf16 h = __float2bfloat16(x);
  return __builtin_bit_cast(unsigned short, h);
}

// async global->LDS 16B copy (lands at wave-uniform base + lane*16)
__device__ __forceinline__ void gll16(const void* g, void* l) {
  __builtin_amdgcn_global_load_lds(
      (const __attribute__((address_space(1))) unsigned int*)g,
      (__attribute__((address_space(3))) unsigned int*)l, 16, 0, 0);
}

// ---------------- cast fp32 -> bf16, 4 elems/thread ----------------
__global__ __launch_bounds__(256) void cast_f32_bf16(const float4* __restrict__ src,
                                                     unsigned long long* __restrict__ dst,
                                                     int n4) {
  int i = blockIdx.x * 256 + threadIdx.x;
  if (i >= n4) return;
  float4 v = src[i];
  unsigned long long r = (unsigned long long)f2bfu(v.x)
                       | ((unsigned long long)f2bfu(v.y) << 16)
                       | ((unsigned long long)f2bfu(v.z) << 32)
                       | ((unsigned long long)f2bfu(v.w) << 48);
  dst[i] = r;
}

// ---------------- GEMM: C[M,N] = A[M,K] * B[N,K]^T (m97-style async staging) ----------------
__device__ inline void store_cvt(float* p, float v) { *p = v; }
__device__ inline void store_cvt(bf16* p, float v) { *p = __float2bfloat16(v); }

template <typename OutT>
__global__ __launch_bounds__(256) void gemm_bt(const bf16* __restrict__ A,
                                               const bf16* __restrict__ B,
                                               OutT* __restrict__ C,
                                               int M, int N, int K) {
  __shared__ __align__(16) bf16 As[128][32];   // unpadded: required by global_load_lds
  __shared__ __align__(16) bf16 Bs[128][32];
  const int tid = threadIdx.x;
  const int wave = tid >> 6, lane = tid & 63;
  const int wm = wave >> 1, wn = wave & 1;
  const int quad = lane >> 4, l16 = lane & 15;
  const int m0 = blockIdx.y * 128, n0 = blockIdx.x * 128;
  const int c0 = tid, c1 = tid + 256;
  const int r0 = c0 >> 2, k0 = (c0 & 3) * 8;
  const int r1 = c1 >> 2, k1 = (c1 & 3) * 8;
  f32x4 acc[4][4] = {};
  for (int kt = 0; kt < K; kt += 32) {
    gll16(&A[(size_t)(m0 + r0) * K + kt + k0], (bf16*)As + (size_t)c0 * 8);
    gll16(&A[(size_t)(m0 + r1) * K + kt + k1], (bf16*)As + (size_t)c1 * 8);
    gll16(&B[(size_t)(n0 + r0) * K + kt + k0], (bf16*)Bs + (size_t)c0 * 8);
    gll16(&B[(size_t)(n0 + r1) * K + kt + k1], (bf16*)Bs + (size_t)c1 * 8);
    __syncthreads();
    short8 af[4], bfr[4];
#pragma unroll
    for (int t = 0; t < 4; t++) {
      af[t]  = *(const short8*)&As[wm * 64 + t * 16 + l16][quad * 8];
      bfr[t] = *(const short8*)&Bs[wn * 64 + t * 16 + l16][quad * 8];
    }
#pragma unroll
    for (int im = 0; im < 4; im++)
#pragma unroll
      for (int in = 0; in < 4; in++)
        acc[im][in] = __builtin_amdgcn_mfma_f32_16x16x32_bf16(af[im], bfr[in], acc[im][in], 0, 0, 0);
    __syncthreads();
  }
#pragma unroll
  for (int im = 0; im < 4; im++)
#pragma unroll
    for (int in = 0; in < 4; in++) {
      int col = n0 + wn * 64 + in * 16 + l16;
#pragma unroll
      for (int r = 0; r < 4; r++) {
        int row = m0 + wm * 64 + im * 16 + quad * 4 + r;
        store_cvt(&C[(size_t)row * N + col], acc[im][in][r]);
      }
    }
}

// ---------------- RMSNorm + RoPE: one wave per (token, slot) row ----------------
// rows = slot*8192 + token, slots 0..19 (16 q + 4 k). V is handled by transpose_v.
// Lane holds d=lane and d=lane+64 — rope partner is in-lane, one sincos per lane.
__global__ __launch_bounds__(256) void norm_rope(const bf16* __restrict__ qkv,
                                                 bf16* __restrict__ qb,
                                                 bf16* __restrict__ kb) {
  const int lane = threadIdx.x & 63;
  const int gw = (blockIdx.x * 256 + threadIdx.x) >> 6;
  const int nw = (gridDim.x * 256) >> 6;
  const float inv_freq = __expf(-(float)lane * (9.210340371976184f / 64.0f));
  for (int row = gw; row < 20 * 8192; row += nw) {
    const int slot = row >> 13, token = row & 8191;
    const int b = token >> 11, t = token & 2047;
    const bf16* src = qkv + (size_t)token * 3072 + slot * 128;
    float x1 = __bfloat162float(src[lane]);
    float x2 = __bfloat162float(src[lane + 64]);
    float ss = x1 * x1 + x2 * x2;
#pragma unroll
    for (int m = 1; m < 64; m <<= 1) ss += __shfl_xor(ss, m, 64);
    float rinv = rsqrtf(ss * (1.0f / 128.0f) + 1.1920929e-7f);
    x1 *= rinv; x2 *= rinv;
    float c, s;
    __sincosf((float)t * inv_freq, &s, &c);
    float o1 = x1 * c + x2 * s;
    float o2 = x2 * c - x1 * s;
    bf16* dst;
    if (slot < 16) {
      o1 *= 0.08838834764831845f;  // fold 1/sqrt(D) into q
      o2 *= 0.08838834764831845f;
      dst = qb + (((size_t)(b * 16 + slot)) * 2048 + t) * 128;
    } else {
      dst = kb + (((size_t)(b * 4 + (slot - 16))) * 2048 + t) * 128;
    }
    dst[lane] = __float2bfloat16(o1);
    dst[lane + 64] = __float2bfloat16(o2);
  }
}

// ---------------- V transpose straight from qkv: -> (s, d, t), s = b*4+hkv ----------------
__global__ __launch_bounds__(256) void transpose_v(const bf16* __restrict__ qkv,
                                                   bf16* __restrict__ vout) {
  __shared__ __align__(16) bf16 til[64][144];
  const int tid = threadIdx.x;
  const int s = blockIdx.y;                 // b*4 + hkv
  const int b = s >> 2, hkv = s & 3;
  const bf16* src = qkv + ((size_t)(b * 2048 + blockIdx.x * 64)) * 3072 + 2560 + hkv * 128;
  bf16* dst = vout + (size_t)s * 128 * 2048 + blockIdx.x * 64;
#pragma unroll
  for (int p = 0; p < 4; p++) {
    int idx = p * 256 + tid;
    *(uint4*)&til[idx >> 4][(idx & 15) * 8] =
        *(const uint4*)&src[(size_t)(idx >> 4) * 3072 + (idx & 15) * 8];
  }
  __syncthreads();
  const int ds = tid & 127;
  const int hs = tid >> 7;
#pragma unroll
  for (int p = 0; p < 4; p++) {
    int c8 = (p * 2 + hs) * 8;
    short8 v;
#pragma unroll
    for (int j = 0; j < 8; j++) v[j] = *(const short*)&til[c8 + j][ds];
    *(short8*)&dst[(size_t)ds * 2048 + c8] = v;
  }
}

// ---------------- causal GQA flash attention (persistent, balanced) ----------------
// 512 blocks = exactly 2/CU. Block i processes items {i, 1023-i}; item = qt*64 + bh.
// qt pairs sum to 15 => every block runs exactly 34 K-tiles. Fixed-shift softmax.
__global__ __launch_bounds__(512, 4) void flash_attn(const bf16* __restrict__ qb,
                                                     const bf16* __restrict__ kb,
                                                     const bf16* __restrict__ vtg,
                                                     bf16* __restrict__ attnb) {
  __shared__ __align__(16) bf16 Ks[64][136];    // 17.4 KB
  __shared__ __align__(16) bf16 Vt[128][72];    // 18.4 KB  [d][t]
  __shared__ __align__(16) bf16 Ps[8][16][72];  // 18.4 KB  per-wave slab

  const int tid = threadIdx.x;
  const int w = tid >> 6, lane = tid & 63;
  const int quad = lane >> 4, l16 = lane & 15;
  const int krow = tid >> 4, kc8 = (tid & 15) * 8;
  const int vrow = tid >> 3, vc8 = (tid & 7) * 8;

  for (int it = 0; it < 2; it++) {
    const int item = it == 0 ? blockIdx.x : 1023 - blockIdx.x;
    const int qt = item >> 6, bh = item & 63;
    const int b = bh >> 4, h = bh & 15, hkv = h >> 2;
    const int q0 = qt * 128;
    const bf16* Q  = qb  + ((size_t)(b * 16 + h) * 2048 + q0) * 128;
    const bf16* Kp = kb  + (size_t)(b * 4 + hkv) * 2048 * 128;
    const bf16* Vg = vtg + (size_t)(b * 4 + hkv) * 128 * 2048;
    const int qw = q0 + w * 16;

    // Q fragments (A-layout), pre-scaled by 1/sqrt(D)
    short8 aq[4];
#pragma unroll
    for (int dk = 0; dk < 4; dk++)
      aq[dk] = *(const short8*)&Q[(size_t)(w * 16 + l16) * 128 + dk * 32 + quad * 8];

    f32x4 o[8] = {};
    float l_i[4] = {0.f, 0.f, 0.f, 0.f};

    const int ntiles = 2 * qt + 2;
    uint4 ka0 = *(const uint4*)&Kp[(size_t)krow * 128 + kc8];
    uint4 ka1 = *(const uint4*)&Kp[(size_t)(krow + 32) * 128 + kc8];
    uint4 va0 = *(const uint4*)&Vg[(size_t)vrow * 2048 + vc8];
    uint4 va1 = *(const uint4*)&Vg[(size_t)(vrow + 64) * 2048 + vc8];

    for (int kt = 0; kt < ntiles; kt++) {
      const int kv0 = kt * 64;
      *(uint4*)&Ks[krow][kc8]      = ka0;
      *(uint4*)&Ks[krow + 32][kc8] = ka1;
      *(uint4*)&Vt[vrow][vc8]      = va0;
      *(uint4*)&Vt[vrow + 64][vc8] = va1;
      __syncthreads();

      // prefetch next tile; flies during compute
      const int nkv0 = min(kv0 + 64, (ntiles - 1) * 64);
      ka0 = *(const uint4*)&Kp[(size_t)(nkv0 + krow) * 128 + kc8];
      ka1 = *(const uint4*)&Kp[(size_t)(nkv0 + krow + 32) * 128 + kc8];
      va0 = *(const uint4*)&Vg[(size_t)vrow * 2048 + nkv0 + vc8];
      va1 = *(const uint4*)&Vg[(size_t)(vrow + 64) * 2048 + nkv0 + vc8];

      if (kv0 <= qw + 15) {  // wave-uniform causal skip
        f32x4 s[4] = {};
#pragma unroll
        for (int nt = 0; nt < 4; nt++)
#pragma unroll
          for (int dk = 0; dk < 4; dk++) {
            short8 bk = *(const short8*)&Ks[nt * 16 + l16][dk * 32 + quad * 8];
            s[nt] = __builtin_amdgcn_mfma_f32_16x16x32_bf16(aq[dk], bk, s[nt], 0, 0, 0);
          }

        // fixed-shift softmax: RMS-normed q,k => |s| <= sqrt(128) < 12
        const bool dtile = (kv0 + 63 > qw);
        const int qrow = qw + quad * 4;
#pragma unroll
        for (int nt = 0; nt < 4; nt++) {
          const int kcol = kv0 + nt * 16 + l16;
#pragma unroll
          for (int r = 0; r < 4; r++) {
            float p = __expf(s[nt][r] - 12.0f);
            if (dtile && kcol > qrow + r) p = 0.f;
            l_i[r] += p;
            Ps[w][quad * 4 + r][nt * 16 + l16] = __float2bfloat16(p);
          }
        }
        __threadfence_block();  // intra-wave RAW on per-wave Ps slab

        short8 ap[2];
#pragma unroll
        for (int kk = 0; kk < 2; kk++)
          ap[kk] = *(const short8*)&Ps[w][l16][kk * 32 + quad * 8];
#pragma unroll
        for (int vt = 0; vt < 8; vt++)
#pragma unroll
          for (int kk = 0; kk < 2; kk++) {
            short8 bv = *(const short8*)&Vt[vt * 16 + l16][kk * 32 + quad * 8];
            o[vt] = __builtin_amdgcn_mfma_f32_16x16x32_bf16(ap[kk], bv, o[vt], 0, 0, 0);
          }
      }
      __syncthreads();
    }

    // epilogue: register-only (safe to overlap with next item's staging)
#pragma unroll
    for (int r = 0; r < 4; r++) {
#pragma unroll
      for (int mm = 1; mm < 16; mm <<= 1) l_i[r] += __shfl_xor(l_i[r], mm, 64);
    }
#pragma unroll
    for (int r = 0; r < 4; r++) {
      float inv = 1.0f / l_i[r];
      int trow = qw + quad * 4 + r;
      size_t base = ((size_t)b * 2048 + trow) * 2048 + h * 128;
#pragma unroll
      for (int vt = 0; vt < 8; vt++)
        attnb[base + vt * 16 + l16] = __float2bfloat16(o[vt][r] * inv);
    }
  }
}

__global__ void finalize(float* out) {
  if (threadIdx.x == 0 && blockIdx.x == 0) out[(size_t)8192 * 2048] = 0.0f;
}

extern "C" void kernel_launch(void* const* d_in, const int* in_sizes, int n_in,
                              void* d_out, int out_size, void* d_ws, size_t ws_size,
                              hipStream_t stream) {
  const float* x  = (const float*)d_in[0];
  const float* Wq = (const float*)d_in[1];
  const float* Wk = (const float*)d_in[2];
  const float* Wv = (const float*)d_in[3];
  const float* Wo = (const float*)d_in[4];
  float* out = (float*)d_out;

  char* ws = (char*)d_ws;
  bf16* xb    = (bf16*)(ws);               // 33.5 MB
  bf16* wqkv  = (bf16*)(ws + 33554432);    // 12.6 MB (dead after QKV gemm)
  bf16* vtb   = (bf16*)(ws + 33554432);    // 8.4 MB, aliases wqkv
  bf16* wob   = (bf16*)(ws + 46137344);    // 8.4 MB
  bf16* qkvb  = (bf16*)(ws + 54525952);    // 50.3 MB
  bf16* qb    = (bf16*)(ws + 104857600);   // 33.5 MB
  bf16* kb    = (bf16*)(ws + 138412032);   // 8.4 MB
  bf16* attnb = qkvb;                      // alias: qkv dead after attention inputs built

  cast_f32_bf16<<<16384, 256, 0, stream>>>((const float4*)x,  (unsigned long long*)xb, 4194304);
  cast_f32_bf16<<<4096,  256, 0, stream>>>((const float4*)Wq, (unsigned long long*)wqkv, 1048576);
  cast_f32_bf16<<<1024,  256, 0, stream>>>((const float4*)Wk, (unsigned long long*)(wqkv + 2048 * 2048), 262144);
  cast_f32_bf16<<<1024,  256, 0, stream>>>((const float4*)Wv, (unsigned long long*)(wqkv + 2560 * 2048), 262144);
  cast_f32_bf16<<<4096,  256, 0, stream>>>((const float4*)Wo, (unsigned long long*)wob, 1048576);

  gemm_bt<bf16><<<dim3(24, 64), 256, 0, stream>>>(xb, wqkv, qkvb, 8192, 3072, 2048);
  norm_rope<<<4096, 256, 0, stream>>>(qkvb, qb, kb);
  transpose_v<<<dim3(32, 16), 256, 0, stream>>>(qkvb, vtb);
  flash_attn<<<512, 512, 0, stream>>>(qb, kb, vtb, attnb);
  gemm_bt<float><<<dim3(16, 64), 256, 0, stream>>>(attnb, wob, out, 8192, 2048, 2048);
  finalize<<<1, 64, 0, stream>>>(out);
}